// Round 1
// baseline (25908.698 us; speedup 1.0000x reference)
//
#include <hip/hip_runtime.h>

// BiLSTM-CRF forward on MI355X.
// Phases:
//   1. wtrans:  transpose W_ih (both dirs) to [k][row] for coalesced GEMM reads; bias sums.
//   2. gin:     gather emb rows + input projection gin_d[t][1024] (reverse dir time-flipped).
//   3. lstm:    persistent 16-WG kernel (8 WG/direction). Each WG owns 32 hidden units
//               (128 gate rows); W_hh slice lives in VGPRs (128 regs/thread). h broadcast
//               via L3 with per-step flag counters (agent-scope atomics).
//   4. feats:   [hf,hr] @ w_out^T + b_out.
//   5. viterbi: 64-lane sequential DP + serial backtrace; writes d_out[0]=score,
//               d_out[1..8193)=path (as f32).

#define SEQ  8192
#define EMBD 256
#define HD   256         // per-direction hidden
#define G4   1024        // 4*H gate rows
#define NWG  8           // workgroups per direction
#define NEGV -10000.0f

__device__ __forceinline__ float sigmf(float x) { return 1.0f / (1.0f + expf(-x)); }

// ---------------------------------------------------------------- init
__global__ void init_kernel(unsigned* flags_f, unsigned* flags_r, float* hfb, float* hrb) {
    int i = blockIdx.x * blockDim.x + threadIdx.x;
    if (i <= SEQ) { flags_f[i] = 0u; flags_r[i] = 0u; }
    if (i < HD)   { hfb[i] = 0.0f; hrb[i] = 0.0f; }
}

// ---------------------------------------------------------------- W_ih transpose + bias sums
__global__ void wtrans_kernel(const float* __restrict__ w_ih_f, const float* __restrict__ w_ih_r,
                              const float* __restrict__ b_ih_f, const float* __restrict__ b_hh_f,
                              const float* __restrict__ b_ih_r, const float* __restrict__ b_hh_r,
                              float* __restrict__ wt_f, float* __restrict__ wt_r,
                              float* __restrict__ bs_f, float* __restrict__ bs_r) {
    int row = blockIdx.x;          // 0..1023
    int k   = threadIdx.x;         // 0..255
    wt_f[(size_t)k * G4 + row] = w_ih_f[(size_t)row * EMBD + k];
    wt_r[(size_t)k * G4 + row] = w_ih_r[(size_t)row * EMBD + k];
    if (k == 0) {
        bs_f[row] = b_ih_f[row] + b_hh_f[row];
        bs_r[row] = b_ih_r[row] + b_hh_r[row];
    }
}

// ---------------------------------------------------------------- input projection
// Block: 32 timesteps. Thread: 8 virtual rows {tid+256m}: m<4 -> fwd, m>=4 -> rev.
__global__ __launch_bounds__(256) void gin_kernel(
    const int* __restrict__ sentence, const float* __restrict__ emb,
    const float* __restrict__ wt_f, const float* __restrict__ wt_r,
    const float* __restrict__ bs_f, const float* __restrict__ bs_r,
    float* __restrict__ gin_f, float* __restrict__ gin_r)
{
    __shared__ float x_lds[32][EMBD];
    __shared__ int   sid_lds[32];
    int t0  = blockIdx.x * 32;
    int tid = threadIdx.x;
    if (tid < 32) sid_lds[tid] = sentence[t0 + tid];
    __syncthreads();
    for (int i = 0; i < 32; ++i)
        x_lds[i][tid] = emb[(size_t)sid_lds[i] * EMBD + tid];
    __syncthreads();

    float bsv[8];
#pragma unroll
    for (int m = 0; m < 4; ++m) bsv[m]     = bs_f[tid + 256 * m];
#pragma unroll
    for (int m = 0; m < 4; ++m) bsv[4 + m] = bs_r[tid + 256 * m];

    for (int tsub = 0; tsub < 4; ++tsub) {
        float acc[8][8];
#pragma unroll
        for (int m = 0; m < 8; ++m)
#pragma unroll
            for (int j = 0; j < 8; ++j) acc[m][j] = bsv[m];

        for (int k = 0; k < EMBD; ++k) {
            float xv[8];
#pragma unroll
            for (int j = 0; j < 8; ++j) xv[j] = x_lds[tsub * 8 + j][k];
#pragma unroll
            for (int m = 0; m < 8; ++m) {
                float wv = (m < 4) ? wt_f[(size_t)k * G4 + tid + 256 * m]
                                   : wt_r[(size_t)k * G4 + tid + 256 * (m - 4)];
#pragma unroll
                for (int j = 0; j < 8; ++j) acc[m][j] = fmaf(wv, xv[j], acc[m][j]);
            }
        }
#pragma unroll
        for (int m = 0; m < 8; ++m) {
            int row = tid + 256 * (m & 3);
#pragma unroll
            for (int j = 0; j < 8; ++j) {
                int t = t0 + tsub * 8 + j;
                if (m < 4) gin_f[(size_t)t * G4 + row] = acc[m][j];
                else       gin_r[(size_t)(SEQ - 1 - t) * G4 + row] = acc[m][j];
            }
        }
    }
}

// ---------------------------------------------------------------- persistent LSTM
// grid = 16 blocks x 256 threads. block b: dir = b&1, slice s = b>>1 (32 units).
// Thread pair (2r,2r+1) computes gate row r over halves of h; W_hh slice in VGPRs.
__global__ __launch_bounds__(256, 1) void lstm_kernel(
    const float* __restrict__ w_hh_f, const float* __restrict__ w_hh_r,
    const float* __restrict__ gin_f, const float* __restrict__ gin_r,
    float* hf_buf, float* hr_buf, unsigned* flags_f, unsigned* flags_r)
{
    int b   = blockIdx.x;
    int dir = b & 1;
    int s   = b >> 1;
    const float* W    = dir ? w_hh_r : w_hh_f;
    const float* gin  = dir ? gin_r  : gin_f;
    float*       hbuf = dir ? hr_buf : hf_buf;
    unsigned*    flags = dir ? flags_r : flags_f;

    int tid = threadIdx.x;
    int r   = tid >> 1;                         // local row 0..127 (= unit*4 + gate)
    int hh  = tid & 1;                          // which half of the 256-dot
    int grow = (r & 3) * 256 + s * 32 + (r >> 2);  // global gate row [i|f|g|o stacked]

    // resident weights: 128 f32 per thread
    float w[128];
    {
        const float4* wrow = reinterpret_cast<const float4*>(&W[(size_t)grow * HD + hh * 128]);
#pragma unroll
        for (int kk = 0; kk < 32; ++kk) {
            float4 v = wrow[kk];
            w[4 * kk + 0] = v.x; w[4 * kk + 1] = v.y;
            w[4 * kk + 2] = v.z; w[4 * kk + 3] = v.w;
        }
    }

    __shared__ float h_lds[HD];
    __shared__ float g_lds[128];

    float c = 0.0f;

    for (int t = 0; t < SEQ; ++t) {
        // independent of h -> issued before the spin, latency hidden
        float gval = gin[(size_t)t * G4 + grow];

        if (t > 0) {
            if (tid == 0) {
                // acquire: invalidates L1/L2 so the h loads below see fresh L3 data
                while (__hip_atomic_load(&flags[t], __ATOMIC_ACQUIRE,
                                         __HIP_MEMORY_SCOPE_AGENT) < NWG) {}
            }
            __syncthreads();
        }
        h_lds[tid] = hbuf[(size_t)t * HD + tid];
        __syncthreads();

        float a0 = 0.f, a1 = 0.f, a2 = 0.f, a3 = 0.f;
        const float4* hv4 = reinterpret_cast<const float4*>(&h_lds[hh * 128]);
#pragma unroll
        for (int kk = 0; kk < 32; ++kk) {
            float4 hv = hv4[kk];
            a0 = fmaf(w[4 * kk + 0], hv.x, a0);
            a1 = fmaf(w[4 * kk + 1], hv.y, a1);
            a2 = fmaf(w[4 * kk + 2], hv.z, a2);
            a3 = fmaf(w[4 * kk + 3], hv.w, a3);
        }
        float tot = (a0 + a1) + (a2 + a3);
        tot += __shfl_xor(tot, 1);
        if (hh == 0) g_lds[r] = tot + gval;
        __syncthreads();

        if (tid < 32) {                          // wave 0: one thread per hidden unit
            float4 g4 = *reinterpret_cast<const float4*>(&g_lds[tid * 4]);
            float ig = sigmf(g4.x);
            float fg = sigmf(g4.y);
            float gg = tanhf(g4.z);
            float og = sigmf(g4.w);
            c = fg * c + ig * gg;
            float hval = og * tanhf(c);
            // write-through (bypasses L1/L2) so vmcnt-retire == agent-visible
            __hip_atomic_store(&hbuf[(size_t)(t + 1) * HD + s * 32 + tid], hval,
                               __ATOMIC_RELAXED, __HIP_MEMORY_SCOPE_AGENT);
            if (tid == 0) {
                // hand-rolled release: wave-level vmcnt(0) covers all 32 lanes' stores
                asm volatile("s_waitcnt vmcnt(0)" ::: "memory");
                __hip_atomic_fetch_add(&flags[t + 1], 1u, __ATOMIC_RELAXED,
                                       __HIP_MEMORY_SCOPE_AGENT);
            }
        }
        // no trailing barrier needed: next iteration's top barrier protects g_lds/h_lds
    }
}

// ---------------------------------------------------------------- feats = [hf,hr] @ w_out^T + b
// grid 32 x 256; thread owns one timestep, acc over all 32 tags.
__global__ __launch_bounds__(256) void feats_kernel(
    const float* __restrict__ hf_buf, const float* __restrict__ hr_buf,
    const float* __restrict__ w_out, const float* __restrict__ b_out,
    float* __restrict__ feats)
{
    __shared__ __align__(16) float wt_lds[256][36];   // [k][tag], padded rows (144B, 16B-aligned)
    int tid = threadIdx.x;
    int t   = blockIdx.x * 256 + tid;

    float acc[32];
#pragma unroll
    for (int g = 0; g < 32; ++g) acc[g] = b_out[g];

    for (int half = 0; half < 2; ++half) {
        __syncthreads();
        for (int tag = 0; tag < 32; ++tag)
            wt_lds[tid][tag] = w_out[tag * 512 + half * 256 + tid];
        __syncthreads();

        const float* hsrc = (half == 0) ? &hf_buf[(size_t)(t + 1) * HD]
                                        : &hr_buf[(size_t)(SEQ - t) * HD];
        for (int k = 0; k < 256; k += 4) {
            float4 hv = *reinterpret_cast<const float4*>(&hsrc[k]);
#pragma unroll
            for (int kk = 0; kk < 4; ++kk) {
                float hx = (kk == 0) ? hv.x : (kk == 1) ? hv.y : (kk == 2) ? hv.z : hv.w;
#pragma unroll
                for (int q = 0; q < 8; ++q) {
                    float4 wv = *reinterpret_cast<const float4*>(&wt_lds[k + kk][4 * q]);
                    acc[4 * q + 0] = fmaf(hx, wv.x, acc[4 * q + 0]);
                    acc[4 * q + 1] = fmaf(hx, wv.y, acc[4 * q + 1]);
                    acc[4 * q + 2] = fmaf(hx, wv.z, acc[4 * q + 2]);
                    acc[4 * q + 3] = fmaf(hx, wv.w, acc[4 * q + 3]);
                }
            }
        }
    }
#pragma unroll
    for (int q = 0; q < 8; ++q) {
        float4 o;
        o.x = acc[4 * q + 0]; o.y = acc[4 * q + 1];
        o.z = acc[4 * q + 2]; o.w = acc[4 * q + 3];
        *reinterpret_cast<float4*>(&feats[(size_t)t * 32 + 4 * q]) = o;
    }
}

// ---------------------------------------------------------------- viterbi + backtrace
// 1 block, 64 threads (one wave): lane = (next_tag n, half ph); 16 prev-tags per lane.
__global__ void viterbi_kernel(const float* __restrict__ feats,
                               const float* __restrict__ transitions,
                               unsigned char* __restrict__ bp,
                               float* __restrict__ out)
{
    __shared__ float v[32];
    int tid = threadIdx.x;
    int n = tid >> 1, ph = tid & 1;

    float T[16];
#pragma unroll
    for (int p = 0; p < 16; ++p) T[p] = transitions[n * 32 + ph * 16 + p];

    if (tid < 32) v[tid] = (tid == 30) ? 0.0f : NEGV;   // START = 30
    __syncthreads();

    float fcur = feats[n];
    for (int t = 0; t < SEQ; ++t) {
        float fnext = (t + 1 < SEQ) ? feats[(size_t)(t + 1) * 32 + n] : 0.0f;

        float best = -3.4e38f; int barg = 0;
#pragma unroll
        for (int p = 0; p < 16; ++p) {
            float sc = v[ph * 16 + p] + T[p];
            if (sc > best) { best = sc; barg = ph * 16 + p; }   // strict > keeps first max
        }
        float ob = __shfl_xor(best, 1);
        int   oa = __shfl_xor(barg, 1);
        // jnp.argmax tie-break = lowest index: low half wins ties
        bool useOther = ph ? (ob >= best) : (ob > best);
        float m = useOther ? ob : best;
        int   a = useOther ? oa : barg;

        __syncthreads();
        if (ph == 0) {
            v[n] = m + fcur;
            bp[(size_t)t * 32 + n] = (unsigned char)a;
        }
        __syncthreads();
        fcur = fnext;
    }

    // terminal = v + transitions[STOP]; argmax with lowest-index tie-break
    float term; int idx;
    if (tid < 32) { term = v[tid] + transitions[31 * 32 + tid]; idx = tid; }
    else          { term = -3.4e38f; idx = 63; }
#pragma unroll
    for (int off = 1; off < 32; off <<= 1) {
        float ot = __shfl_xor(term, off);
        int   oi = __shfl_xor(idx, off);
        if (ot > term || (ot == term && oi < idx)) { term = ot; idx = oi; }
    }
    if (tid == 0) {
        out[0] = term;
        int tag = idx;
        out[1 + (SEQ - 1)] = (float)tag;
        for (int t = SEQ - 2; t >= 0; --t) {
            tag = bp[(size_t)(t + 1) * 32 + tag];
            out[1 + t] = (float)tag;
        }
    }
}

// ---------------------------------------------------------------- launch
extern "C" void kernel_launch(void* const* d_in, const int* in_sizes, int n_in,
                              void* d_out, int out_size, void* d_ws, size_t ws_size,
                              hipStream_t stream)
{
    const int*   sentence = (const int*)d_in[0];
    const float* emb      = (const float*)d_in[1];
    const float* w_ih_f   = (const float*)d_in[2];
    const float* w_hh_f   = (const float*)d_in[3];
    const float* b_ih_f   = (const float*)d_in[4];
    const float* b_hh_f   = (const float*)d_in[5];
    const float* w_ih_r   = (const float*)d_in[6];
    const float* w_hh_r   = (const float*)d_in[7];
    const float* b_ih_r   = (const float*)d_in[8];
    const float* b_hh_r   = (const float*)d_in[9];
    const float* w_out    = (const float*)d_in[10];
    const float* b_out    = (const float*)d_in[11];
    const float* trans    = (const float*)d_in[12];
    (void)in_sizes; (void)n_in; (void)out_size;

    char* ws = (char*)d_ws;
    size_t off = 0;
    auto alloc = [&](size_t bytes) -> void* {
        void* p = (void*)(ws + off);
        off += (bytes + 255) & ~(size_t)255;
        return p;
    };
    float*    gin_f  = (float*)alloc((size_t)SEQ * G4 * 4);        // 32 MB
    float*    gin_r  = (float*)alloc((size_t)SEQ * G4 * 4);        // 32 MB
    float*    hfb    = (float*)alloc((size_t)(SEQ + 1) * HD * 4);  // 8 MB
    float*    hrb    = (float*)alloc((size_t)(SEQ + 1) * HD * 4);  // 8 MB
    float*    wt_f   = (float*)alloc((size_t)EMBD * G4 * 4);       // 1 MB
    float*    wt_r   = (float*)alloc((size_t)EMBD * G4 * 4);       // 1 MB
    float*    bs_f   = (float*)alloc(G4 * 4);
    float*    bs_r   = (float*)alloc(G4 * 4);
    unsigned* flg_f  = (unsigned*)alloc((size_t)(SEQ + 1) * 4);
    unsigned* flg_r  = (unsigned*)alloc((size_t)(SEQ + 1) * 4);
    float*    feats  = (float*)alloc((size_t)SEQ * 32 * 4);        // 1 MB
    unsigned char* bp = (unsigned char*)alloc((size_t)SEQ * 32);   // 256 KB
    (void)ws_size;  // ~87.4 MB needed

    init_kernel<<<(SEQ + 256) / 256 + 1, 256, 0, stream>>>(flg_f, flg_r, hfb, hrb);
    wtrans_kernel<<<G4, 256, 0, stream>>>(w_ih_f, w_ih_r, b_ih_f, b_hh_f, b_ih_r, b_hh_r,
                                          wt_f, wt_r, bs_f, bs_r);
    gin_kernel<<<SEQ / 32, 256, 0, stream>>>(sentence, emb, wt_f, wt_r, bs_f, bs_r,
                                             gin_f, gin_r);
    lstm_kernel<<<2 * NWG, 256, 0, stream>>>(w_hh_f, w_hh_r, gin_f, gin_r,
                                             hfb, hrb, flg_f, flg_r);
    feats_kernel<<<SEQ / 256, 256, 0, stream>>>(hfb, hrb, w_out, b_out, feats);
    viterbi_kernel<<<1, 64, 0, stream>>>(feats, trans, bp, (float*)d_out);
}